// Round 10
// baseline (75.582 us; speedup 1.0000x reference)
//
#include <hip/hip_runtime.h>
#include <hip/hip_bf16.h>
#include <cmath>

#define PHI_F   1.6180339887498949f
#define INV2PI  0.15915494309189535f
#define SQRT2F  1.41421356237309505f
#define TLASTF  (63.0f * 1.6180339887498949f)
#define LOG2EF  1.4426950408889634f

#define AG  __HIP_MEMORY_SCOPE_AGENT
#define RLX __ATOMIC_RELAXED

typedef __attribute__((ext_vector_type(8))) short bf16x8;
typedef __attribute__((ext_vector_type(4))) float f32x4;

__device__ __forceinline__ unsigned short bf16rn(float x) {
    const unsigned u = __float_as_uint(x);
    return (unsigned short)((u + 0x7fffu + ((u >> 16) & 1u)) >> 16);
}

__device__ __forceinline__ bf16x8 cvt8(float4 a, float4 b) {
    union { bf16x8 v; __hip_bfloat162 h2[4]; } u;
    u.h2[0] = __float22bfloat162_rn(make_float2(a.x, a.y));
    u.h2[1] = __float22bfloat162_rn(make_float2(a.z, a.w));
    u.h2[2] = __float22bfloat162_rn(make_float2(b.x, b.y));
    u.h2[3] = __float22bfloat162_rn(make_float2(b.z, b.w));
    return u.v;
}

__device__ __forceinline__ float silu_add(float h0, float s) {
    const float sig = __builtin_amdgcn_rcpf(
        1.0f + __builtin_amdgcn_exp2f(-LOG2EF * s));
    return h0 + s * sig;
}

// --- device-coherent (sc1 / LLC) accessors: NO cache-maintenance ops -------
__device__ __forceinline__ void st16(unsigned short* p, unsigned short v) {
    __hip_atomic_store(p, v, RLX, AG);
}
__device__ __forceinline__ void stf(float* p, float v) {
    __hip_atomic_store((unsigned*)p, __float_as_uint(v), RLX, AG);
}
__device__ __forceinline__ float ldf(const float* p) {
    return __uint_as_float(__hip_atomic_load((unsigned*)p, RLX, AG));
}
__device__ __forceinline__ bf16x8 ld8bf(const unsigned short* p) {
    union { unsigned long long q[2]; bf16x8 v; } u;
    u.q[0] = __hip_atomic_load((unsigned long long*)p,       RLX, AG);
    u.q[1] = __hip_atomic_load((unsigned long long*)(p + 4), RLX, AG);
    return u.v;
}

// Fence-free grid barrier: __syncthreads drains this block's stores
// (compiler emits vmcnt(0) before s_barrier); relaxed RMW arrive + relaxed
// poll, both sc1 at the LLC coherence point. No wbl2, no inv.
__device__ __forceinline__ void phasebar(unsigned* cnt) {
    __syncthreads();
    if (threadIdx.x == 0) {
        asm volatile("s_waitcnt vmcnt(0)" ::: "memory");
        __hip_atomic_fetch_add(cnt, 1u, RLX, AG);
        while (__hip_atomic_load(cnt, RLX, AG) < 256u)
            __builtin_amdgcn_s_sleep(2);
    }
    __syncthreads();
}

// 16x16 NT fragment: A = bf16 activations via sc1 8B atomic loads,
// B = fp32 weights via NORMAL cached loads, cvt'd inline. 1 MFMA / 32-k.
// C/D: col = lane&15, row = 4*(lane>>4) + reg  [verified r1]
template<int KC>
__device__ __forceinline__ f32x4 fragA(
    const unsigned short* __restrict__ Ab, int lda, int arow,
    const float* __restrict__ Bp, int ldb, int brow, int k0, int lane)
{
    const int rr = lane & 15, ko = (lane >> 4) * 8;
    const unsigned short* ap = Ab + (size_t)(arow + rr) * lda + k0 + ko;
    const float*          bp = Bp + (size_t)(brow + rr) * ldb + k0 + ko;
    f32x4 acc = {0.f, 0.f, 0.f, 0.f};
    #pragma unroll
    for (int kk = 0; kk < KC; kk += 32) {
        const bf16x8 ah = ld8bf(ap + kk);
        const float4 b0 = *(const float4*)(bp + kk);
        const float4 b1 = *(const float4*)(bp + kk + 4);
        acc = __builtin_amdgcn_mfma_f32_16x16x32_bf16(ah, cvt8(b0, b1), acc, 0, 0, 0);
    }
    return acc;
}

// ---- theta: ct/st = cos/sin(h @ W^T + bias + t); 2 tiles/block, ksplit 4 ---
__device__ __forceinline__ void theta_phase(
    int bid, int lane, int w, float (*red)[260],
    const unsigned short* hhA, const float* Wl, const float* biasl,
    unsigned short* ct, unsigned short* st)
{
    const int tile = bid * 2 + (w >> 2);
    const int mt = tile >> 6, nt = tile & 63;
    const f32x4 acc = fragA<128>(hhA, 512, mt * 16, Wl, 512, nt * 16,
                                 (w & 3) * 128, lane);
    *(f32x4*)&red[w][lane * 4] = acc;
    __syncthreads();
    if ((w & 3) < 2) {
        const int grp = (w >> 2) * 4;
        float4 s = {0.f, 0.f, 0.f, 0.f};
        #pragma unroll
        for (int ww = 0; ww < 4; ++ww) {
            const float4 q = *(const float4*)&red[grp + ww][lane * 4];
            s.x += q.x; s.y += q.y; s.z += q.z; s.w += q.w;
        }
        const int sel = w & 3;
        unsigned short* dst = sel ? st : ct;
        const int col = lane & 15, rb = (lane >> 4) * 4;
        const int n = nt * 16 + col;
        const float bn = biasl[n] + TLASTF;
        const float sv[4] = {s.x, s.y, s.z, s.w};
        #pragma unroll
        for (int r = 0; r < 4; ++r) {
            const int m = mt * 16 + rb + r;
            const float fr = __builtin_amdgcn_fractf((sv[r] + bn) * INV2PI);
            const float vv = sel ? __builtin_amdgcn_sinf(fr)
                                 : __builtin_amdgcn_cosf(fr);
            st16(dst + m * 1024 + n, bf16rn(vv));
        }
    }
}

// ---- pv: h' = h + silu(ct@Pr^T + st@Pi^T); pair=w>>2, ksplit 4 (KC=256) ---
template<bool CARRY>
__device__ __forceinline__ void pv_phase(
    int bid, int lane, int w, float (*red)[260],
    const unsigned short* ct, const unsigned short* st,
    const float* Prl, const float* Pil,
    const float* hin, float* hout, unsigned short* hhout)
{
    const int mt = bid >> 5, nt = bid & 31;
    const int p = w >> 2, k0 = (w & 3) * 256;
    const unsigned short* A = p ? st : ct;
    const float* Bp = p ? Pil : Prl;
    const f32x4 acc = fragA<256>(A, 1024, mt * 16, Bp, 1024, nt * 16, k0, lane);
    *(f32x4*)&red[w][lane * 4] = acc;
    __syncthreads();
    if (w == 0) {
        float4 s = {0.f, 0.f, 0.f, 0.f};
        #pragma unroll
        for (int ww = 0; ww < 8; ++ww) {
            const float4 q = *(const float4*)&red[ww][lane * 4];
            s.x += q.x; s.y += q.y; s.z += q.z; s.w += q.w;
        }
        const int col = lane & 15, rb = (lane >> 4) * 4;
        const int dn = nt * 16 + col;
        const float sv[4] = {s.x, s.y, s.z, s.w};
        #pragma unroll
        for (int r = 0; r < 4; ++r) {
            const int m = mt * 16 + rb + r;
            const float val = silu_add(ldf(hin + m * 512 + dn), sv[r]);
            if (CARRY) stf(hout + m * 512 + dn, val);
            st16(hhout + m * 512 + dn, bf16rn(val));
        }
    }
}

// ---------------------------------------------------------------------------
// Single persistent kernel: 256 blocks x 512 thr (1 block/CU, co-resident).
// rec | th0 | pv0 | th1 | pv1 | logits, 5 fence-free barriers.
// Inter-phase activations (~1MB) go via sc1/LLC; weights stay L2-cached.
// ---------------------------------------------------------------------------
__global__ __launch_bounds__(512) void mega(
    const int* __restrict__ ids, const float* __restrict__ te,
    const float* __restrict__ W, const float* __restrict__ bias,
    const float* __restrict__ Pr, const float* __restrict__ Pi,
    const float* __restrict__ op, float* __restrict__ out,
    unsigned* __restrict__ cnt,
    unsigned short* __restrict__ hh0, float* __restrict__ h0,
    unsigned short* __restrict__ ct, unsigned short* __restrict__ st,
    unsigned short* __restrict__ hh1, float* __restrict__ h1,
    unsigned short* __restrict__ hh2)
{
    __shared__ float red[8][260];
    __shared__ int sid[64];
    const int tid = threadIdx.x, bid = blockIdx.x;
    const int lane = tid & 63, w = tid >> 6;

    // ---------------- P0: rotation recurrence (blocks 0..127) -------------
    if (bid < 128) {
        if (tid < 64) sid[tid] = ids[bid * 64 + tid];
        __syncthreads();
        const int d = tid;
        float wv[2][8], bev[2][8];
        #pragma unroll
        for (int j = 0; j < 8; ++j) {
            const int id = sid[j];
            wv[0][j]  = te[id * 1024 + d];
            bev[0][j] = te[id * 1024 + 512 + d];
        }
        float v = 0.f;
        #pragma unroll
        for (int g = 0; g < 8; ++g) {
            const int cur = g & 1, nxt = cur ^ 1;
            if (g < 7) {
                #pragma unroll
                for (int j = 0; j < 8; ++j) {
                    const int id = sid[(g + 1) * 8 + j];
                    wv[nxt][j]  = te[id * 1024 + d];
                    bev[nxt][j] = te[id * 1024 + 512 + d];
                }
            }
            #pragma unroll
            for (int j = 0; j < 8; ++j) {
                const int t = g * 8 + j;
                const float rlam = __builtin_amdgcn_rcpf(1.0f + fabsf(wv[cur][j]));
                const float a2 = (SQRT2F * INV2PI) * rlam;
                const float b2 = fmaf(2.0f * INV2PI, bev[cur][j],
                                      fmaf((float)t, 2.0f * PHI_F * INV2PI, 0.125f));
                v = __builtin_amdgcn_sinf(__builtin_amdgcn_fractf(fmaf(v, a2, b2)));
            }
        }
        const float u = SQRT2F * v;
        stf(h0 + bid * 512 + d, u);
        st16(hh0 + bid * 512 + d, bf16rn(u));
    }
    phasebar(cnt + 0);

    theta_phase(bid, lane, w, red, hh0, W, bias, ct, st);
    phasebar(cnt + 16);

    pv_phase<true>(bid, lane, w, red, ct, st, Pr, Pi, h0, h1, hh1);
    phasebar(cnt + 32);

    theta_phase(bid, lane, w, red, hh1, W + 524288, bias + 1024, ct, st);
    phasebar(cnt + 48);

    pv_phase<false>(bid, lane, w, red, ct, st, Pr + 524288, Pi + 524288,
                    h1, nullptr, hh2);
    phasebar(cnt + 64);

    // ---------------- logits: 2 tiles/block, ksplit 4, normal stores ------
    {
        const int tile = bid * 2 + (w >> 2);
        const int mt = tile >> 6, nt = tile & 63;
        const f32x4 acc = fragA<128>(hh2, 512, mt * 16, op, 512, nt * 16,
                                     (w & 3) * 128, lane);
        *(f32x4*)&red[w][lane * 4] = acc;
        __syncthreads();
        if ((w & 3) == 0) {
            const int grp = (w >> 2) * 4;
            float4 s = {0.f, 0.f, 0.f, 0.f};
            #pragma unroll
            for (int ww = 0; ww < 4; ++ww) {
                const float4 q = *(const float4*)&red[grp + ww][lane * 4];
                s.x += q.x; s.y += q.y; s.z += q.z; s.w += q.w;
            }
            const int col = lane & 15, rb = (lane >> 4) * 4;
            const int n = nt * 16 + col;
            const float sv[4] = {s.x, s.y, s.z, s.w};
            #pragma unroll
            for (int r = 0; r < 4; ++r)
                out[(size_t)(mt * 16 + rb + r) * 1024 + n] = sv[r];
        }
    }
}

// ---------------------------------------------------------------------------
// B=128, S=64, V=1024, D=512, N=1024, L=2 — memset + 1 kernel node.
// ws: cnt 5x64B | hh0 | h0 | ct | st | hh1 | h1 | hh2  (~1.4 MiB)
// ---------------------------------------------------------------------------
extern "C" void kernel_launch(void* const* d_in, const int* in_sizes, int n_in,
                              void* d_out, int out_size, void* d_ws, size_t ws_size,
                              hipStream_t stream) {
    const int*   ids   = (const int*)d_in[0];
    const float* te    = (const float*)d_in[1];
    const float* W     = (const float*)d_in[2];
    const float* bias  = (const float*)d_in[3];
    const float* Pr    = (const float*)d_in[4];
    const float* Pi    = (const float*)d_in[5];
    const float* oproj = (const float*)d_in[6];
    float* out = (float*)d_out;

    unsigned*       cnt = (unsigned*)d_ws;                      // 5 x 64B lines
    unsigned short* hh0 = (unsigned short*)((char*)d_ws + 512); // 65,536
    float*          h0  = (float*)(hh0 + 65536);                // 65,536
    unsigned short* ct  = (unsigned short*)(h0 + 65536);        // 131,072
    unsigned short* st  = ct + 131072;                          // 131,072
    unsigned short* hh1 = st + 131072;                          // 65,536
    float*          h1  = (float*)(hh1 + 65536);                // 65,536
    unsigned short* hh2 = (unsigned short*)(h1 + 65536);        // 65,536

    hipMemsetAsync(d_ws, 0, 512, stream);   // zero barrier counters
    mega<<<256, 512, 0, stream>>>(ids, te, W, bias, Pr, Pi, oproj, out,
                                  cnt, hh0, h0, ct, st, hh1, h1, hh2);
}

// Round 12
// 65.936 us; speedup vs baseline: 1.1463x; 1.1463x over previous
//
#include <hip/hip_runtime.h>
#include <hip/hip_bf16.h>
#include <cmath>

#define PHI_F   1.6180339887498949f
#define INV2PI  0.15915494309189535f
#define SQRT2F  1.41421356237309505f
#define TLASTF  (63.0f * 1.6180339887498949f)
#define LOG2EF  1.4426950408889634f

#define AG  __HIP_MEMORY_SCOPE_AGENT
#define RLX __ATOMIC_RELAXED

typedef __attribute__((ext_vector_type(8))) short bf16x8;
typedef __attribute__((ext_vector_type(4))) float f32x4;

__device__ __forceinline__ unsigned short bf16rn(float x) {
    const unsigned u = __float_as_uint(x);
    return (unsigned short)((u + 0x7fffu + ((u >> 16) & 1u)) >> 16);
}

__device__ __forceinline__ bf16x8 cvt8(float4 a, float4 b) {
    union { bf16x8 v; __hip_bfloat162 h2[4]; } u;
    u.h2[0] = __float22bfloat162_rn(make_float2(a.x, a.y));
    u.h2[1] = __float22bfloat162_rn(make_float2(a.z, a.w));
    u.h2[2] = __float22bfloat162_rn(make_float2(b.x, b.y));
    u.h2[3] = __float22bfloat162_rn(make_float2(b.z, b.w));
    return u.v;
}

__device__ __forceinline__ float silu_add(float h0, float s) {
    const float sig = __builtin_amdgcn_rcpf(
        1.0f + __builtin_amdgcn_exp2f(-LOG2EF * s));
    return h0 + s * sig;
}

// --- device-coherent accessors (sc0/sc1 at LLC coherence point; never emits
//     wbl2/inv cache maintenance) -------------------------------------------
__device__ __forceinline__ void st16a(unsigned short* p, unsigned short v) {
    __hip_atomic_store(p, v, RLX, AG);
}
__device__ __forceinline__ void stf(float* p, float v) {
    __hip_atomic_store((unsigned*)p, __float_as_uint(v), RLX, AG);
}
__device__ __forceinline__ float ldf(const float* p) {
    return __uint_as_float(__hip_atomic_load((unsigned*)p, RLX, AG));
}
// vectorized 16B device-coherent load (staging only)
__device__ __forceinline__ float4 ld16dc(const void* p) {
    float4 r;
    asm volatile("global_load_dwordx4 %0, %1, off sc0 sc1"
                 : "=&v"(r) : "v"(p) : "memory");
    return r;
}
__device__ __forceinline__ void stage_fence() {
    asm volatile("s_waitcnt vmcnt(0)" ::: "memory");
    __builtin_amdgcn_sched_barrier(0);
}

// Fence-free grid barrier: every thread drains its own vmem (all sc1 stores
// reach the coherence point), then one relaxed RMW arrive + relaxed poll.
// MUST be reached by ALL threads of the block (no divergent barriers!).
__device__ __forceinline__ void phasebar(unsigned* cnt) {
    asm volatile("s_waitcnt vmcnt(0)" ::: "memory");
    __syncthreads();
    if (threadIdx.x == 0) {
        __hip_atomic_fetch_add(cnt, 1u, RLX, AG);
        while (__hip_atomic_load(cnt, RLX, AG) < 256u)
            __builtin_amdgcn_s_sleep(2);
    }
    __syncthreads();
}

// ---------------------------------------------------------------------------
// Persistent kernel v4: 256 blocks x 1024 thr (16 waves, 1 block/CU).
// rec | th0 | pv0 | th1 | pv1 | logits, 5 fence-free barriers.
// Activations staged block-locally into LDS via 16B sc1 loads; GEMM A-reads
// from LDS; B = fp32 weights via normal cached loads (read once, stay in L2).
// ---------------------------------------------------------------------------
__global__ __launch_bounds__(1024) void mega(
    const int* __restrict__ ids, const float* __restrict__ te,
    const float* __restrict__ W, const float* __restrict__ bias,
    const float* __restrict__ Pr, const float* __restrict__ Pi,
    const float* __restrict__ op, float* __restrict__ out,
    unsigned* __restrict__ cnt,
    unsigned short* __restrict__ hh0, float* __restrict__ h0,
    unsigned short* __restrict__ ct, unsigned short* __restrict__ st,
    unsigned short* __restrict__ hh1, float* __restrict__ h1,
    unsigned short* __restrict__ hh2)
{
    __shared__ float red[16][260];                 // 16.6 KB
    __shared__ unsigned short sA[2][16][1032];     // 66.0 KB (pad: 516dw%32=4)
    __shared__ int sid[64];
    const int tid = threadIdx.x, bid = blockIdx.x;
    const int lane = tid & 63, w = tid >> 6;       // 16 waves
    const int rr = lane & 15, ko = (lane >> 4) * 8;
    const int col = lane & 15, rb = (lane >> 4) * 4;

    // ================= P0: rotation recurrence (blocks 0..127) ============
    // NOTE: barrier is block-uniform (bid is uniform); only the compute body
    // is thread-divergent. r11's bug was tid<512 around the __syncthreads.
    if (bid < 128) {
        if (tid < 64) sid[tid] = ids[bid * 64 + tid];
        __syncthreads();
        if (tid < 512) {
            const int d = tid;
            float wv[2][8], bev[2][8];
            #pragma unroll
            for (int j = 0; j < 8; ++j) {
                const int id = sid[j];
                wv[0][j]  = te[id * 1024 + d];
                bev[0][j] = te[id * 1024 + 512 + d];
            }
            float v = 0.f;
            #pragma unroll
            for (int g = 0; g < 8; ++g) {
                const int cur = g & 1, nxt = cur ^ 1;
                if (g < 7) {
                    #pragma unroll
                    for (int j = 0; j < 8; ++j) {
                        const int id = sid[(g + 1) * 8 + j];
                        wv[nxt][j]  = te[id * 1024 + d];
                        bev[nxt][j] = te[id * 1024 + 512 + d];
                    }
                }
                #pragma unroll
                for (int j = 0; j < 8; ++j) {
                    const int t = g * 8 + j;
                    const float rlam = __builtin_amdgcn_rcpf(1.0f + fabsf(wv[cur][j]));
                    const float a2 = (SQRT2F * INV2PI) * rlam;
                    const float b2 = fmaf(2.0f * INV2PI, bev[cur][j],
                                          fmaf((float)t, 2.0f * PHI_F * INV2PI, 0.125f));
                    v = __builtin_amdgcn_sinf(__builtin_amdgcn_fractf(fmaf(v, a2, b2)));
                }
            }
            const float u = SQRT2F * v;
            stf(h0 + bid * 512 + d, u);
            st16a(hh0 + bid * 512 + d, bf16rn(u));
        }
    }
    phasebar(cnt + 0);

    // ================= layers ============
    #pragma unroll 1
    for (int l = 0; l < 2; ++l) {
        const float* Wl  = W  + (size_t)l * 524288;
        const float* Prl = Pr + (size_t)l * 524288;
        const float* Pil = Pi + (size_t)l * 524288;
        const unsigned short* hhin = l ? hh1 : hh0;
        const float* hin = l ? h1 : h0;

        // ---- theta: 2 tiles/block (same mt), 8-way ksplit KC=64 ----------
        {
            const int mt16 = (bid >> 5) * 16;
            {   // stage A strip 16x512 bf16 via sc1
                const int row = tid >> 6, c8 = (tid & 63) * 8;
                const float4 v = ld16dc(hhin + (size_t)(mt16 + row) * 512 + c8);
                stage_fence();
                *(float4*)&sA[0][row][c8] = v;
            }
            __syncthreads();
            const int tile = bid * 2 + (w >> 3);
            const int nt = tile & 63;
            const int k0 = (w & 7) * 64;
            const unsigned short* ap = &sA[0][rr][k0 + ko];
            const float* bp = Wl + (size_t)(nt * 16 + rr) * 512 + k0 + ko;
            f32x4 acc = {0.f, 0.f, 0.f, 0.f};
            #pragma unroll
            for (int kk = 0; kk < 64; kk += 32) {
                const bf16x8 ah = *(const bf16x8*)(ap + kk);
                const float4 b0 = *(const float4*)(bp + kk);
                const float4 b1 = *(const float4*)(bp + kk + 4);
                acc = __builtin_amdgcn_mfma_f32_16x16x32_bf16(ah, cvt8(b0, b1), acc, 0, 0, 0);
            }
            *(f32x4*)&red[w][lane * 4] = acc;
            __syncthreads();
            if ((w & 7) < 2) {
                const int grp = (w >> 3) * 8;
                float4 s = {0.f, 0.f, 0.f, 0.f};
                #pragma unroll
                for (int ww = 0; ww < 8; ++ww) {
                    const float4 q = *(const float4*)&red[grp + ww][lane * 4];
                    s.x += q.x; s.y += q.y; s.z += q.z; s.w += q.w;
                }
                const int sel = w & 7;
                unsigned short* dst = sel ? st : ct;
                const int n = nt * 16 + col;
                const float bn = bias[l * 1024 + n] + TLASTF;
                const float sv[4] = {s.x, s.y, s.z, s.w};
                #pragma unroll
                for (int r = 0; r < 4; ++r) {
                    const int m = mt16 + rb + r;
                    const float fr = __builtin_amdgcn_fractf((sv[r] + bn) * INV2PI);
                    const float vv = sel ? __builtin_amdgcn_sinf(fr)
                                         : __builtin_amdgcn_cosf(fr);
                    st16a(dst + m * 1024 + n, bf16rn(vv));
                }
            }
        }
        phasebar(cnt + 16 + 32 * l);

        // ---- pv: 1 tile/block, pair = w>>3, 8-way ksplit KC=128 ----------
        {
            const int mt16 = (bid >> 5) * 16, nt = bid & 31;
            {   // stage ct/st strips 2 x 16x1024 bf16 via sc1
                const int row = tid >> 6, c8 = (tid & 63) * 8;
                const float4 v0 = ld16dc(ct + (size_t)(mt16 + row) * 1024 + c8);
                const float4 v1 = ld16dc(ct + (size_t)(mt16 + row) * 1024 + c8 + 512);
                const float4 v2 = ld16dc(st + (size_t)(mt16 + row) * 1024 + c8);
                const float4 v3 = ld16dc(st + (size_t)(mt16 + row) * 1024 + c8 + 512);
                stage_fence();
                *(float4*)&sA[0][row][c8]       = v0;
                *(float4*)&sA[0][row][c8 + 512] = v1;
                *(float4*)&sA[1][row][c8]       = v2;
                *(float4*)&sA[1][row][c8 + 512] = v3;
            }
            __syncthreads();
            const int p = w >> 3, k0 = (w & 7) * 128;
            const float* Bp = p ? Pil : Prl;
            const unsigned short* ap = &sA[p][rr][k0 + ko];
            const float* bp = Bp + (size_t)(nt * 16 + rr) * 1024 + k0 + ko;
            f32x4 acc = {0.f, 0.f, 0.f, 0.f};
            #pragma unroll
            for (int kk = 0; kk < 128; kk += 32) {
                const bf16x8 ah = *(const bf16x8*)(ap + kk);
                const float4 b0 = *(const float4*)(bp + kk);
                const float4 b1 = *(const float4*)(bp + kk + 4);
                acc = __builtin_amdgcn_mfma_f32_16x16x32_bf16(ah, cvt8(b0, b1), acc, 0, 0, 0);
            }
            *(f32x4*)&red[w][lane * 4] = acc;
            __syncthreads();
            if (w == 0) {
                float4 s = {0.f, 0.f, 0.f, 0.f};
                #pragma unroll
                for (int ww = 0; ww < 16; ++ww) {
                    const float4 q = *(const float4*)&red[ww][lane * 4];
                    s.x += q.x; s.y += q.y; s.z += q.z; s.w += q.w;
                }
                const int dn = nt * 16 + col;
                const float sv[4] = {s.x, s.y, s.z, s.w};
                #pragma unroll
                for (int r = 0; r < 4; ++r) {
                    const int m = mt16 + rb + r;
                    const float val = silu_add(ldf(hin + m * 512 + dn), sv[r]);
                    if (l == 0) stf(h1 + m * 512 + dn, val);
                    st16a((l ? hh2 : hh1) + m * 512 + dn, bf16rn(val));
                }
            }
        }
        phasebar(cnt + 32 + 32 * l);
    }

    // ================= logits: 2 tiles/block, 8-way ksplit KC=64 ==========
    {
        const int mt16 = (bid >> 5) * 16;
        {
            const int row = tid >> 6, c8 = (tid & 63) * 8;
            const float4 v = ld16dc(hh2 + (size_t)(mt16 + row) * 512 + c8);
            stage_fence();
            *(float4*)&sA[0][row][c8] = v;
        }
        __syncthreads();
        const int tile = bid * 2 + (w >> 3);
        const int nt = tile & 63;
        const int k0 = (w & 7) * 64;
        const unsigned short* ap = &sA[0][rr][k0 + ko];
        const float* bp = op + (size_t)(nt * 16 + rr) * 512 + k0 + ko;
        f32x4 acc = {0.f, 0.f, 0.f, 0.f};
        #pragma unroll
        for (int kk = 0; kk < 64; kk += 32) {
            const bf16x8 ah = *(const bf16x8*)(ap + kk);
            const float4 b0 = *(const float4*)(bp + kk);
            const float4 b1 = *(const float4*)(bp + kk + 4);
            acc = __builtin_amdgcn_mfma_f32_16x16x32_bf16(ah, cvt8(b0, b1), acc, 0, 0, 0);
        }
        *(f32x4*)&red[w][lane * 4] = acc;
        __syncthreads();
        if ((w & 7) == 0) {
            const int grp = (w >> 3) * 8;
            float4 s = {0.f, 0.f, 0.f, 0.f};
            #pragma unroll
            for (int ww = 0; ww < 8; ++ww) {
                const float4 q = *(const float4*)&red[grp + ww][lane * 4];
                s.x += q.x; s.y += q.y; s.z += q.z; s.w += q.w;
            }
            const int n = nt * 16 + col;
            const float sv[4] = {s.x, s.y, s.z, s.w};
            #pragma unroll
            for (int r = 0; r < 4; ++r)
                out[(size_t)(mt16 + rb + r) * 1024 + n] = sv[r];
        }
    }
}

// ---------------------------------------------------------------------------
// B=128, S=64, V=1024, D=512, N=1024, L=2 — memset + 1 kernel node.
// ws: cnt 5x64B | hh0 | h0 | ct | st | hh1 | h1 | hh2  (~1.4 MiB)
// ---------------------------------------------------------------------------
extern "C" void kernel_launch(void* const* d_in, const int* in_sizes, int n_in,
                              void* d_out, int out_size, void* d_ws, size_t ws_size,
                              hipStream_t stream) {
    const int*   ids   = (const int*)d_in[0];
    const float* te    = (const float*)d_in[1];
    const float* W     = (const float*)d_in[2];
    const float* bias  = (const float*)d_in[3];
    const float* Pr    = (const float*)d_in[4];
    const float* Pi    = (const float*)d_in[5];
    const float* oproj = (const float*)d_in[6];
    float* out = (float*)d_out;

    unsigned*       cnt = (unsigned*)d_ws;                      // 5 x 64B lines
    unsigned short* hh0 = (unsigned short*)((char*)d_ws + 512); // 65,536
    float*          h0  = (float*)(hh0 + 65536);                // 65,536
    unsigned short* ct  = (unsigned short*)(h0 + 65536);        // 131,072
    unsigned short* st  = ct + 131072;                          // 131,072
    unsigned short* hh1 = st + 131072;                          // 65,536
    float*          h1  = (float*)(hh1 + 65536);                // 65,536
    unsigned short* hh2 = (unsigned short*)(h1 + 65536);        // 65,536

    hipMemsetAsync(d_ws, 0, 512, stream);   // zero barrier counters
    mega<<<256, 1024, 0, stream>>>(ids, te, W, bias, Pr, Pi, oproj, out,
                                   cnt, hh0, h0, ct, st, hh1, h1, hh2);
}

// Round 13
// 42.429 us; speedup vs baseline: 1.7814x; 1.5540x over previous
//
#include <hip/hip_runtime.h>
#include <hip/hip_bf16.h>
#include <cmath>

#define PHI_F   1.6180339887498949f
#define INV2PI  0.15915494309189535f
#define SQRT2F  1.41421356237309505f
#define TLASTF  (63.0f * 1.6180339887498949f)
#define LOG2EF  1.4426950408889634f

typedef __attribute__((ext_vector_type(8))) short bf16x8;
typedef __attribute__((ext_vector_type(4))) float f32x4;

__device__ __forceinline__ unsigned short bf16rn(float x) {
    const unsigned u = __float_as_uint(x);
    return (unsigned short)((u + 0x7fffu + ((u >> 16) & 1u)) >> 16);
}

// 8x fp32 -> bf16x8 (RN-even), inline weight conversion
__device__ __forceinline__ bf16x8 cvt8(float4 a, float4 b) {
    union { bf16x8 v; __hip_bfloat162 h2[4]; } u;
    u.h2[0] = __float22bfloat162_rn(make_float2(a.x, a.y));
    u.h2[1] = __float22bfloat162_rn(make_float2(a.z, a.w));
    u.h2[2] = __float22bfloat162_rn(make_float2(b.x, b.y));
    u.h2[3] = __float22bfloat162_rn(make_float2(b.z, b.w));
    return u.v;
}

// ---------------------------------------------------------------------------
// Recurrence: 256 blocks x 256 thr (b = bid>>1, d = (bid&1)*256+tid).
// Depth-8 register prefetch hides te-gather latency under the serial sin chain.
// ---------------------------------------------------------------------------
__global__ __launch_bounds__(256) void rinrec_k(
    const int* __restrict__ ids, const float* __restrict__ te,
    float* __restrict__ h, unsigned short* __restrict__ hh)
{
    const int b = blockIdx.x >> 1;
    const int d = ((blockIdx.x & 1) << 8) + threadIdx.x;
    __shared__ int sid[64];
    if (threadIdx.x < 64) sid[threadIdx.x] = ids[b * 64 + threadIdx.x];
    __syncthreads();

    float wv[2][8], bev[2][8];
    #pragma unroll
    for (int j = 0; j < 8; ++j) {
        const int id = sid[j];
        wv[0][j]  = te[id * 1024 + d];
        bev[0][j] = te[id * 1024 + 512 + d];
    }
    float v = 0.f;
    #pragma unroll
    for (int g = 0; g < 8; ++g) {
        const int cur = g & 1, nxt = cur ^ 1;
        if (g < 7) {
            #pragma unroll
            for (int j = 0; j < 8; ++j) {
                const int id = sid[(g + 1) * 8 + j];
                wv[nxt][j]  = te[id * 1024 + d];
                bev[nxt][j] = te[id * 1024 + 512 + d];
            }
        }
        #pragma unroll
        for (int j = 0; j < 8; ++j) {
            const int t = g * 8 + j;
            const float rlam = __builtin_amdgcn_rcpf(1.0f + fabsf(wv[cur][j]));
            const float a2 = (SQRT2F * INV2PI) * rlam;
            const float b2 = fmaf(2.0f * INV2PI, bev[cur][j],
                                  fmaf((float)t, 2.0f * PHI_F * INV2PI, 0.125f));
            v = __builtin_amdgcn_sinf(__builtin_amdgcn_fractf(fmaf(v, a2, b2)));
        }
    }
    const float u = SQRT2F * v;
    h[b * 512 + d] = u;
    hh[b * 512 + d] = bf16rn(u);
}

// ---------------------------------------------------------------------------
// 16x16 NT fragment: A = bf16 activations, B = fp32 weights cvt'd inline.
// 3 x 16B loads + 1 MFMA per 32-wide k-step, fully unrolled (KC/32 iters).
// C/D: col = lane&15, row = 4*(lane>>4) + reg
// ---------------------------------------------------------------------------
template<int KC>
__device__ __forceinline__ f32x4 frag1(
    const unsigned short* __restrict__ Ah, const float* __restrict__ B,
    int lda, int ldb, int m0, int n0, int k0, int lane)
{
    const int rr = lane & 15;
    const int ko = (lane >> 4) * 8;
    const unsigned short* ap = Ah + (size_t)(m0 + rr) * lda + k0 + ko;
    const float*          bp = B  + (size_t)(n0 + rr) * ldb + k0 + ko;
    f32x4 acc = {0.f, 0.f, 0.f, 0.f};
    #pragma unroll
    for (int kk = 0; kk < KC; kk += 32) {
        const bf16x8 ah = *(const bf16x8*)(ap + kk);
        const float4 b0 = *(const float4*)(bp + kk);
        const float4 b1 = *(const float4*)(bp + kk + 4);
        acc = __builtin_amdgcn_mfma_f32_16x16x32_bf16(ah, cvt8(b0, b1), acc, 0, 0, 0);
    }
    return acc;
}

// ---------------------------------------------------------------------------
// theta: ct/st = cos/sin(h @ W^T + bias + t_last), bf16.
// M=128,N=1024,K=512. 512 blocks (1 tile: mt=bid>>6, nt=bid&63) x 8 waves
// (split-K KC=64) -> 16 waves/CU.
// ---------------------------------------------------------------------------
__global__ __launch_bounds__(512) void theta_k(
    const unsigned short* __restrict__ hh,
    const float* __restrict__ W, const float* __restrict__ bias,
    unsigned short* __restrict__ ct, unsigned short* __restrict__ st)
{
    __shared__ float red[8][260];
    const int lane = threadIdx.x & 63;
    const int w = threadIdx.x >> 6;
    const int nt = blockIdx.x & 63, mt = blockIdx.x >> 6;
    const f32x4 acc = frag1<64>(hh, W, 512, 512,
                                mt * 16, nt * 16, w * 64, lane);
    *(f32x4*)&red[w][lane * 4] = acc;
    __syncthreads();
    if (w < 2) {
        float4 s = {0.f, 0.f, 0.f, 0.f};
        #pragma unroll
        for (int ww = 0; ww < 8; ++ww) {
            const float4 q = *(const float4*)&red[ww][lane * 4];
            s.x += q.x; s.y += q.y; s.z += q.z; s.w += q.w;
        }
        unsigned short* dst = w ? st : ct;
        const int col = lane & 15, rb = (lane >> 4) * 4;
        const int n = nt * 16 + col;
        const float bn = bias[n] + TLASTF;
        const float sv[4] = {s.x, s.y, s.z, s.w};
        #pragma unroll
        for (int r = 0; r < 4; ++r) {
            const int m = mt * 16 + rb + r;
            const float fr = __builtin_amdgcn_fractf((sv[r] + bn) * INV2PI);
            const float vv = w ? __builtin_amdgcn_sinf(fr)
                               : __builtin_amdgcn_cosf(fr);
            dst[m * 1024 + n] = bf16rn(vv);
        }
    }
}

// ---------------------------------------------------------------------------
// pv: h += silu(ct @ Pr^T + st @ Pi^T); h rewritten fp32 + bf16.
// M=128,N=512,K=1024 per pair. 256 blocks (mt=bid>>5, nt=bid&31) x 16 waves
// (pair = w>>3, k-chunk KC=128) -> 16 waves/CU.
// ---------------------------------------------------------------------------
__global__ __launch_bounds__(1024) void pv_k(
    const unsigned short* __restrict__ ct, const unsigned short* __restrict__ st,
    const float* __restrict__ Pr, const float* __restrict__ Pi,
    float* __restrict__ h, unsigned short* __restrict__ hh)
{
    __shared__ float red[16][260];
    const int lane = threadIdx.x & 63;
    const int w = threadIdx.x >> 6;
    const int nt = blockIdx.x & 31, mt = blockIdx.x >> 5;
    const int p = w >> 3, k0 = (w & 7) * 128;
    const unsigned short* A = p ? st : ct;
    const float* B = p ? Pi : Pr;
    const f32x4 acc = frag1<128>(A, B, 1024, 1024,
                                 mt * 16, nt * 16, k0, lane);
    *(f32x4*)&red[w][lane * 4] = acc;
    __syncthreads();
    if (w == 0) {
        float4 s = {0.f, 0.f, 0.f, 0.f};
        #pragma unroll
        for (int ww = 0; ww < 16; ++ww) {
            const float4 q = *(const float4*)&red[ww][lane * 4];
            s.x += q.x; s.y += q.y; s.z += q.z; s.w += q.w;
        }
        const int col = lane & 15, rb = (lane >> 4) * 4;
        const int dn = nt * 16 + col;
        const float sv[4] = {s.x, s.y, s.z, s.w};
        #pragma unroll
        for (int r = 0; r < 4; ++r) {
            const int m = mt * 16 + rb + r;
            const float x = sv[r];
            const float sig = __builtin_amdgcn_rcpf(
                1.0f + __builtin_amdgcn_exp2f(-LOG2EF * x));
            const float val = h[m * 512 + dn] + x * sig;
            h[m * 512 + dn] = val;
            hh[m * 512 + dn] = bf16rn(val);
        }
    }
}

// ---------------------------------------------------------------------------
// logits = h @ oproj^T  (M=128,N=1024,K=512). 512 blocks x 8 waves (KC=64).
// ---------------------------------------------------------------------------
__global__ __launch_bounds__(512) void logits_k(
    const unsigned short* __restrict__ hh,
    const float* __restrict__ op, float* __restrict__ out)
{
    __shared__ float red[8][260];
    const int lane = threadIdx.x & 63;
    const int w = threadIdx.x >> 6;
    const int nt = blockIdx.x & 63, mt = blockIdx.x >> 6;
    const f32x4 acc = frag1<64>(hh, op, 512, 512,
                                mt * 16, nt * 16, w * 64, lane);
    *(f32x4*)&red[w][lane * 4] = acc;
    __syncthreads();
    if (w == 0) {
        float4 s = {0.f, 0.f, 0.f, 0.f};
        #pragma unroll
        for (int ww = 0; ww < 8; ++ww) {
            const float4 q = *(const float4*)&red[ww][lane * 4];
            s.x += q.x; s.y += q.y; s.z += q.z; s.w += q.w;
        }
        const int col = lane & 15, rb = (lane >> 4) * 4;
        const int n = nt * 16 + col;
        const float sv[4] = {s.x, s.y, s.z, s.w};
        #pragma unroll
        for (int r = 0; r < 4; ++r)
            out[(size_t)(mt * 16 + rb + r) * 1024 + n] = sv[r];
    }
}

// ---------------------------------------------------------------------------
// B=128, S=64, V=1024, D=512, N=1024, L=2
// ws: h 65,536 f32 | hh 65,536 us | ct/st 131,072 us  (~0.9 MiB)
// ---------------------------------------------------------------------------
extern "C" void kernel_launch(void* const* d_in, const int* in_sizes, int n_in,
                              void* d_out, int out_size, void* d_ws, size_t ws_size,
                              hipStream_t stream) {
    const int*   ids   = (const int*)d_in[0];
    const float* te    = (const float*)d_in[1];
    const float* W     = (const float*)d_in[2];
    const float* bias  = (const float*)d_in[3];
    const float* Pr    = (const float*)d_in[4];
    const float* Pi    = (const float*)d_in[5];
    const float* oproj = (const float*)d_in[6];
    float* out = (float*)d_out;

    float*          h  = (float*)d_ws;                  // 65,536 f32
    unsigned short* hh = (unsigned short*)(h + 65536);  // 65,536
    unsigned short* ct = hh + 65536;                    // 131,072
    unsigned short* st = ct + 131072;                   // 131,072

    rinrec_k<<<256, 256, 0, stream>>>(ids, te, h, hh);

    for (int l = 0; l < 2; ++l) {
        theta_k<<<512, 512, 0, stream>>>(
            hh, W + (size_t)l * 524288, bias + l * 1024, ct, st);
        pv_k<<<256, 1024, 0, stream>>>(
            ct, st, Pr + (size_t)l * 524288, Pi + (size_t)l * 524288, h, hh);
    }

    logits_k<<<512, 512, 0, stream>>>(hh, oproj, out);
}